// Round 3
// baseline (30.721 us; speedup 1.0000x reference)
//
#include <hip/hip_runtime.h>
#include <hip/hip_bf16.h>

// The node dimension of this model is degenerate: cur starts as broadcast(z)
// (node-constant), contents are node-constant, and a gather of a node-constant
// tensor is node-constant. So the [64, 65536, 1] output is one scalar per
// batch element broadcast over 65536 nodes; p0..p4 are irrelevant.
//
// Dtype evidence so far:
//   - round 1 (all-bf16 reads) -> NaN  => float inputs are f32 (f32 mantissa
//     halves read as bf16 give inf/NaN exponents).
//   - round 2 (bf16 output)   -> 0.532 error > 0.314 (zeros baseline)
//     => output buffer is f32 (reference output dtype), my bf16 packing
//     aliased two batches per f32 word.
//   - studies/tasks/contrasts: reference relies on jax default int width,
//     could be int32 or int64 -> sniff (int64 small values have all-zero
//     high words; int32 random 0..200 cannot have 32 zero odd words).
// Both sniffs are deterministic functions of the input data.
//
// Kernel 1: per-batch scalar chain (64 blocks x 64 threads) -> d_ws (64 f32).
// Kernel 2: broadcast-fill 16 MB f32 output, float4 coalesced stores.

__device__ __forceinline__ float LD(const void* p, int i, int F) {
    if (F) return ((const float*)p)[i];
    return __bfloat162float(((const __hip_bfloat16*)p)[i]);
}

__device__ __forceinline__ int IDX(const void* p, int i, int I64) {
    if (I64) return (int)((const long long*)p)[i];
    return ((const int*)p)[i];
}

__global__ __launch_bounds__(64) void fgl_chain_kernel(
    const void* __restrict__ z,
    const void* __restrict__ studies, const void* __restrict__ tasks,
    const void* __restrict__ contrasts,
    const void* __restrict__ emb_s_v, const void* __restrict__ emb_s_g,
    const void* __restrict__ emb_t_v, const void* __restrict__ emb_t_g,
    const void* __restrict__ emb_c_v, const void* __restrict__ emb_c_g,
    const void* __restrict__ fc0_w, const void* __restrict__ fc0_b,
    const void* __restrict__ fc1_w, const void* __restrict__ fc1_b,
    const void* __restrict__ fc2_w, const void* __restrict__ fc2_b,
    const void* __restrict__ fc3_w, const void* __restrict__ fc3_b,
    const void* __restrict__ fc4_w, const void* __restrict__ fc4_b,
    const void* __restrict__ W0, const void* __restrict__ b0,
    const void* __restrict__ W1, const void* __restrict__ b1,
    const void* __restrict__ W2, const void* __restrict__ b2,
    const void* __restrict__ W3, const void* __restrict__ b3,
    const void* __restrict__ W4, const void* __restrict__ b4,
    float* __restrict__ out_scalar)
{
    const int b = blockIdx.x;   // batch element
    const int t = threadIdx.x;  // 0..63

    __shared__ int F_s;               // 1 = float inputs are f32, 0 = bf16
    __shared__ int I_s;               // 1 = index inputs are int64, 0 = int32
    __shared__ float cat3[48];        // [se | te | ce]
    __shared__ float contents[5][16];
    __shared__ float x[160];          // level input vector (max 144)

    if (t == 0) {
        // float-width sniff on z: bits 7..14 of each word are the bf16
        // exponent if bf16 (never >= 0x89 for N(0,1) data) but random f32
        // mantissa bits if f32 (>= 0x89 with p~0.46/word).
        const unsigned int* w = (const unsigned int*)z;
        int f = 0;
        for (int i = 0; i < 32; ++i) {
            unsigned int e = (w[i] >> 7) & 0xFF;
            if (e >= 0x89) f = 1;
        }
        F_s = f;
        // int-width sniff on contrasts (values 0..199): int64 => all high
        // words zero; int32 => odd elements random, all-zero prob ~200^-32.
        const unsigned int* cw = (const unsigned int*)contrasts;
        int i64 = 1;
        for (int i = 0; i < 32; ++i) if (cw[2 * i + 1] != 0u) i64 = 0;
        I_s = i64;
    }
    __syncthreads();
    const int F = F_s;
    const int I = I_s;

    // ---- weight-normed embeddings: e = g * v / ||v|| ----
    if (t < 48) {
        const int g = t >> 4, j = t & 15;
        const void* v; int row; float gain;
        if (g == 0)      { row = IDX(studies, b, I);   v = emb_s_v; gain = LD(emb_s_g, row, F); }
        else if (g == 1) { row = IDX(tasks, b, I);     v = emb_t_v; gain = LD(emb_t_g, row, F); }
        else             { row = IDX(contrasts, b, I); v = emb_c_v; gain = LD(emb_c_g, row, F); }
        float n2 = 0.f;
        #pragma unroll
        for (int k = 0; k < 16; ++k) { float vv = LD(v, row * 16 + k, F); n2 += vv * vv; }
        cat3[t] = gain * LD(v, row * 16 + j, F) * rsqrtf(n2);
    }
    __syncthreads();

    // ---- content FCs ----
    {
        const int i = t >> 4, j = t & 15;
        const void *fw, *fb; int flen;
        if (i == 0)      { fw = fc0_w; fb = fc0_b; flen = 16; }
        else if (i == 1) { fw = fc1_w; fb = fc1_b; flen = 32; }
        else if (i == 2) { fw = fc2_w; fb = fc2_b; flen = 48; }
        else             { fw = fc3_w; fb = fc3_b; flen = 48; }
        float acc = LD(fb, j, F);
        for (int k = 0; k < flen; ++k) acc += cat3[k] * LD(fw, k * 16 + j, F);
        contents[i][j] = acc;
        if (t < 16) {
            float a4 = LD(fc4_b, t, F);
            for (int k = 0; k < 48; ++k) a4 += cat3[k] * LD(fc4_w, k * 16 + t, F);
            contents[4][t] = a4;
        }
    }
    __syncthreads();

    // ---- x = [z (128) | c0 (16)] ----
    x[t]      = LD(z, b * 128 + t, F);
    x[64 + t] = LD(z, b * 128 + 64 + t, F);
    if (t < 16) x[128 + t] = contents[0][t];
    __syncthreads();

    float h = 0.f;

    // level 0: 144 -> 64, lrelu(0.2)
    {
        float acc = LD(b0, t, F);
        for (int k = 0; k < 144; ++k) acc += x[k] * LD(W0, k * 64 + t, F);
        h = (acc >= 0.f) ? acc : 0.2f * acc;
    }
    __syncthreads();
    x[t] = h;
    if (t < 16) x[64 + t] = contents[1][t];
    __syncthreads();

    // level 1: 80 -> 32
    if (t < 32) {
        float acc = LD(b1, t, F);
        for (int k = 0; k < 80; ++k) acc += x[k] * LD(W1, k * 32 + t, F);
        h = (acc >= 0.f) ? acc : 0.2f * acc;
    }
    __syncthreads();
    if (t < 32) x[t] = h;
    if (t < 16) x[32 + t] = contents[2][t];
    __syncthreads();

    // level 2: 48 -> 16
    if (t < 16) {
        float acc = LD(b2, t, F);
        for (int k = 0; k < 48; ++k) acc += x[k] * LD(W2, k * 16 + t, F);
        h = (acc >= 0.f) ? acc : 0.2f * acc;
    }
    __syncthreads();
    if (t < 16) x[t] = h;
    if (t < 16) x[16 + t] = contents[3][t];
    __syncthreads();

    // level 3: 32 -> 8   (16 activations + 16 content; CH_IN[3]=32)
    if (t < 8) {
        float acc = LD(b3, t, F);
        for (int k = 0; k < 32; ++k) acc += x[k] * LD(W3, k * 8 + t, F);
        h = (acc >= 0.f) ? acc : 0.2f * acc;
    }
    __syncthreads();
    if (t < 8)  x[t] = h;
    if (t < 16) x[8 + t] = contents[4][t];
    __syncthreads();

    // level 4: 24 -> 1, no activation
    if (t == 0) {
        float acc = LD(b4, 0, F);
        for (int k = 0; k < 24; ++k) acc += x[k] * LD(W4, k, F);
        out_scalar[b] = acc;
    }
}

__global__ __launch_bounds__(256) void fgl_fill_kernel(
    const float* __restrict__ scal, float* __restrict__ out)
{
    // 64 batches x 65536 nodes, f32 out; 4 floats per thread (16 B stores).
    // 65536/4 = 16384 vec4 per batch; total 1048576 threads = 4096 x 256.
    const int g = blockIdx.x * 256 + threadIdx.x;
    const int b = g >> 14;
    const float v = scal[b];
    float4 val = make_float4(v, v, v, v);
    reinterpret_cast<float4* __restrict__>(out)[g] = val;
}

extern "C" void kernel_launch(void* const* d_in, const int* in_sizes, int n_in,
                              void* d_out, int out_size, void* d_ws, size_t ws_size,
                              hipStream_t stream) {
    const void* z        = d_in[0];
    const void* studies  = d_in[1];
    const void* tasks    = d_in[2];
    const void* contrasts= d_in[3];
    // d_in[4..8] = p0..p4 — mathematically irrelevant (node-constant activations)
    const void* emb_s_v = d_in[9];
    const void* emb_s_g = d_in[10];
    const void* emb_t_v = d_in[11];
    const void* emb_t_g = d_in[12];
    const void* emb_c_v = d_in[13];
    const void* emb_c_g = d_in[14];
    const void* fc0_w = d_in[15]; const void* fc0_b = d_in[16];
    const void* fc1_w = d_in[17]; const void* fc1_b = d_in[18];
    const void* fc2_w = d_in[19]; const void* fc2_b = d_in[20];
    const void* fc3_w = d_in[21]; const void* fc3_b = d_in[22];
    const void* fc4_w = d_in[23]; const void* fc4_b = d_in[24];
    const void* W0 = d_in[25]; const void* b0 = d_in[26];
    const void* W1 = d_in[27]; const void* b1 = d_in[28];
    const void* W2 = d_in[29]; const void* b2 = d_in[30];
    const void* W3 = d_in[31]; const void* b3 = d_in[32];
    const void* W4 = d_in[33]; const void* b4 = d_in[34];

    float* scal = (float*)d_ws;  // 64 floats

    fgl_chain_kernel<<<64, 64, 0, stream>>>(
        z, studies, tasks, contrasts,
        emb_s_v, emb_s_g, emb_t_v, emb_t_g, emb_c_v, emb_c_g,
        fc0_w, fc0_b, fc1_w, fc1_b, fc2_w, fc2_b, fc3_w, fc3_b, fc4_w, fc4_b,
        W0, b0, W1, b1, W2, b2, W3, b3, W4, b4, scal);

    fgl_fill_kernel<<<4096, 256, 0, stream>>>(scal, (float*)d_out);
}

// Round 4
// 15.439 us; speedup vs baseline: 1.9898x; 1.9898x over previous
//
#include <hip/hip_runtime.h>
#include <hip/hip_bf16.h>

// Node dimension is degenerate: cur starts as broadcast(z) (node-constant),
// contents are node-constant, a gather of a node-constant tensor is
// node-constant. Output [64,65536,1] = one scalar per batch broadcast over
// 65536 nodes; p0..p4 irrelevant.
//
// Round-3 lesson (rocprof): runtime-dtype-branch loads serialized the chain
// kernel to 48us (waitcnt per load). This round: sniff once (ballot), then
// dispatch to template<F,I>-specialized code with clean batchable loads,
// plus split-K across 256 threads to shorten per-thread load chains.
//
// Kernel 1: per-batch chain (64 blocks x 256 threads) -> d_ws (64 f32).
// Kernel 2: broadcast-fill 16 MB f32 output, float4 coalesced stores.

template <int F>
__device__ __forceinline__ float LDF(const void* p, int i) {
    if (F) return ((const float*)p)[i];
    return __bfloat162float(((const __hip_bfloat16*)p)[i]);
}
template <int I>
__device__ __forceinline__ int IDXT(const void* p, int i) {
    if (I) return (int)((const long long*)p)[i];
    return ((const int*)p)[i];
}

struct ChainArgs {
    const void *z, *studies, *tasks, *contrasts;
    const void *emb_s_v, *emb_s_g, *emb_t_v, *emb_t_g, *emb_c_v, *emb_c_g;
    const void *fc_w[5], *fc_b[5];
    const void *W[5], *bias[5];
    float* out_scalar;
};

template <int F, int I>
__device__ __forceinline__ void chain_impl(
    const ChainArgs& a, int b, int t,
    float* cat3, float* contents, float* xa, float* xb, float* partial)
{
    // ---- weight-normed embeddings: e = g * v / ||v|| ----
    if (t < 48) {
        const int g = t >> 4, j = t & 15;
        const void* v; int row; float gain;
        if (g == 0)      { row = IDXT<I>(a.studies, b);   v = a.emb_s_v; gain = LDF<F>(a.emb_s_g, row); }
        else if (g == 1) { row = IDXT<I>(a.tasks, b);     v = a.emb_t_v; gain = LDF<F>(a.emb_t_g, row); }
        else             { row = IDXT<I>(a.contrasts, b); v = a.emb_c_v; gain = LDF<F>(a.emb_c_g, row); }
        float n2 = 0.f;
        #pragma unroll
        for (int k = 0; k < 16; ++k) { float vv = LDF<F>(v, row * 16 + k); n2 += vv * vv; }
        cat3[t] = gain * LDF<F>(v, row * 16 + j) * rsqrtf(n2);
    }
    __syncthreads();

    // ---- content FCs: contents[i] = catX @ fc_w[i] + fc_b[i], i<5 ----
    if (t < 80) {
        const int i = t >> 4, j = t & 15;
        const int flen = (i == 0) ? 16 : (i == 1) ? 32 : 48;
        const void* fw = a.fc_w[i];
        float acc = LDF<F>(a.fc_b[i], j);
        for (int k = 0; k < flen; ++k) acc += cat3[k] * LDF<F>(fw, k * 16 + j);
        contents[i * 16 + j] = acc;
    }
    __syncthreads();

    // ---- xa = [z (128) | c0 (16)] ----
    if (t < 128)      xa[t] = LDF<F>(a.z, b * 128 + t);
    else if (t < 144) xa[t] = contents[t - 128];
    __syncthreads();

    // ---- L0: 144 -> 64, 4-way split-K (wave w = k-chunk w) ----
    {
        const int j = t & 63, q = t >> 6;
        float acc = 0.f;
        #pragma unroll
        for (int k = q * 36; k < q * 36 + 36; ++k) acc += xa[k] * LDF<F>(a.W[0], k * 64 + j);
        partial[q * 64 + j] = acc;
    }
    __syncthreads();
    if (t < 64) {
        float acc = LDF<F>(a.bias[0], t) + partial[t] + partial[64 + t] + partial[128 + t] + partial[192 + t];
        xb[t] = (acc >= 0.f) ? acc : 0.2f * acc;
    } else if (t < 80) xb[t] = contents[16 + (t - 64)];
    __syncthreads();

    // ---- L1: 80 -> 32, 8-way split-K ----
    {
        const int j = t & 31, q = t >> 5;
        float acc = 0.f;
        #pragma unroll
        for (int k = q * 10; k < q * 10 + 10; ++k) acc += xb[k] * LDF<F>(a.W[1], k * 32 + j);
        partial[q * 32 + j] = acc;
    }
    __syncthreads();
    if (t < 32) {
        float acc = LDF<F>(a.bias[1], t);
        #pragma unroll
        for (int q = 0; q < 8; ++q) acc += partial[q * 32 + t];
        xa[t] = (acc >= 0.f) ? acc : 0.2f * acc;
    } else if (t < 48) xa[t] = contents[32 + (t - 32)];
    __syncthreads();

    // ---- L2: 48 -> 16, 16-way split-K ----
    {
        const int j = t & 15, q = t >> 4;
        float acc = 0.f;
        #pragma unroll
        for (int k = q * 3; k < q * 3 + 3; ++k) acc += xa[k] * LDF<F>(a.W[2], k * 16 + j);
        partial[q * 16 + j] = acc;
    }
    __syncthreads();
    if (t < 16) {
        float acc = LDF<F>(a.bias[2], t);
        #pragma unroll
        for (int q = 0; q < 16; ++q) acc += partial[q * 16 + t];
        xb[t] = (acc >= 0.f) ? acc : 0.2f * acc;
    } else if (t < 32) xb[t] = contents[48 + (t - 16)];
    __syncthreads();

    // ---- L3: 32 -> 8, 32-way split-K (k == q) ----
    {
        const int j = t & 7, q = t >> 3;
        partial[q * 8 + j] = xb[q] * LDF<F>(a.W[3], q * 8 + j);
    }
    __syncthreads();
    if (t < 8) {
        float acc = LDF<F>(a.bias[3], t);
        #pragma unroll
        for (int q = 0; q < 32; ++q) acc += partial[q * 8 + t];
        xa[t] = (acc >= 0.f) ? acc : 0.2f * acc;
    } else if (t < 24) xa[t] = contents[64 + (t - 8)];
    __syncthreads();

    // ---- L4: 24 -> 1, no activation ----
    if (t < 24) partial[t] = xa[t] * LDF<F>(a.W[4], t);
    __syncthreads();
    if (t == 0) {
        float acc = LDF<F>(a.bias[4], 0);
        #pragma unroll
        for (int k = 0; k < 24; ++k) acc += partial[k];
        a.out_scalar[b] = acc;
    }
}

__global__ __launch_bounds__(256) void fgl_chain_kernel(ChainArgs a)
{
    const int b = blockIdx.x;   // batch element
    const int t = threadIdx.x;  // 0..255

    __shared__ int FI_s;
    __shared__ float cat3[48];
    __shared__ float contents[80];
    __shared__ float xa[160];
    __shared__ float xb[96];
    __shared__ float partial[256];

    // dtype sniff, one load per lane, wave 0 only:
    //  F: any of z's first 32 words has bf16-exponent(low half) >= 0x89
    //     -> f32 (random mantissa bits); real N(0,1) bf16 never does.
    //  I: contrasts (values 0..199) int64 => 32 high words all zero;
    //     int32 => odd words random, all-zero prob ~200^-32.
    if (t < 64) {
        bool fcond = false, icond = false;
        if (t < 32) {
            unsigned int wz = ((const unsigned int*)a.z)[t];
            fcond = ((wz >> 7) & 0xFF) >= 0x89;
            icond = (((const unsigned int*)a.contrasts)[2 * t + 1] != 0u);
        }
        unsigned long long bf = __ballot(fcond);
        unsigned long long bi = __ballot(icond);
        if (t == 0) FI_s = (bf ? 1 : 0) | ((bi == 0ull) ? 2 : 0);
    }
    __syncthreads();
    const int FI = FI_s;

    if (FI == 1)      chain_impl<1, 0>(a, b, t, cat3, contents, xa, xb, partial);
    else if (FI == 3) chain_impl<1, 1>(a, b, t, cat3, contents, xa, xb, partial);
    else if (FI == 0) chain_impl<0, 0>(a, b, t, cat3, contents, xa, xb, partial);
    else              chain_impl<0, 1>(a, b, t, cat3, contents, xa, xb, partial);
}

__global__ __launch_bounds__(256) void fgl_fill_kernel(
    const float* __restrict__ scal, float* __restrict__ out)
{
    // 64 batches x 65536 nodes, f32; 4 floats/thread (16 B stores).
    // 65536/4 = 16384 vec4 per batch; 4096 blocks x 256 threads.
    const int g = blockIdx.x * 256 + threadIdx.x;
    const int b = g >> 14;
    const float v = scal[b];
    reinterpret_cast<float4* __restrict__>(out)[g] = make_float4(v, v, v, v);
}

extern "C" void kernel_launch(void* const* d_in, const int* in_sizes, int n_in,
                              void* d_out, int out_size, void* d_ws, size_t ws_size,
                              hipStream_t stream) {
    ChainArgs a;
    a.z = d_in[0];
    a.studies = d_in[1];
    a.tasks = d_in[2];
    a.contrasts = d_in[3];
    // d_in[4..8] = p0..p4 — mathematically irrelevant
    a.emb_s_v = d_in[9];  a.emb_s_g = d_in[10];
    a.emb_t_v = d_in[11]; a.emb_t_g = d_in[12];
    a.emb_c_v = d_in[13]; a.emb_c_g = d_in[14];
    for (int i = 0; i < 5; ++i) {
        a.fc_w[i] = d_in[15 + 2 * i];
        a.fc_b[i] = d_in[16 + 2 * i];
        a.W[i]    = d_in[25 + 2 * i];
        a.bias[i] = d_in[26 + 2 * i];
    }
    a.out_scalar = (float*)d_ws;  // 64 floats

    fgl_chain_kernel<<<64, 256, 0, stream>>>(a);
    fgl_fill_kernel<<<4096, 256, 0, stream>>>(a.out_scalar, (float*)d_out);
}

// Round 5
// 13.967 us; speedup vs baseline: 2.1995x; 1.1054x over previous
//
#include <hip/hip_runtime.h>
#include <hip/hip_bf16.h>

// Node dimension is degenerate: cur starts as broadcast(z) (node-constant),
// contents node-constant, gather of node-constant is node-constant. Output
// [64,65536,1] = one scalar per batch broadcast over 65536 nodes.
//
// Round-4 lesson: two-kernel split leaves ~10 us of chain latency + launch
// serialization. This round: ONE fused kernel, 512 blocks; each block
// redundantly computes its batch's scalar chain (weights L2-hot, ~1-2 us
// latency) with ALL weights register-prefetched upfront (no per-phase load
// stalls), then fills its 32 KB output slice at the HBM write roofline.

template <int F>
__device__ __forceinline__ float LDF(const void* p, int i) {
    if (F) return ((const float*)p)[i];
    return __bfloat162float(((const __hip_bfloat16*)p)[i]);
}
template <int I>
__device__ __forceinline__ int IDXT(const void* p, int i) {
    if (I) return (int)((const long long*)p)[i];
    return ((const int*)p)[i];
}

struct ChainArgs {
    const void *z, *studies, *tasks, *contrasts;
    const void *emb_s_v, *emb_s_g, *emb_t_v, *emb_t_g, *emb_c_v, *emb_c_g;
    const void *fc_w[5], *fc_b[5];
    const void *W[5], *bias[5];
};

struct Smem {
    float cat3[48];      // [se | te | ce]
    float contents[80];  // only [16..80) used (c1..c4); c0 goes straight to xa
    float xa[160];
    float xb[96];
    float partial[256];
    float res;
};

__device__ __forceinline__ float lrelu(float a) { return fmaxf(a, 0.2f * a); }

template <int F, int I>
__device__ __forceinline__ void chain_fill(
    const ChainArgs& a, float* __restrict__ out, int b, int slice, int t, Smem& sm)
{
    // ================= register prefetch: all independent loads =================
    // z slice (threads 48..175 stage xa[0..128) in the E phase)
    float zr = 0.f;
    if (t >= 48 && t < 176) zr = LDF<F>(a.z, b * 128 + (t - 48));

    // embedding index (dependent chain root) — issue ASAP
    int row = 0;
    if (t < 48) {
        const int g = t >> 4;
        if (g == 0)      row = IDXT<I>(a.studies, b);
        else if (g == 1) row = IDXT<I>(a.tasks, b);
        else             row = IDXT<I>(a.contrasts, b);
    }

    // FGL weights, per-phase thread mappings, statically unrolled
    float w0r[36];
    {   const int j = t & 63, q = t >> 6;
        #pragma unroll
        for (int k = 0; k < 36; ++k) w0r[k] = LDF<F>(a.W[0], (q * 36 + k) * 64 + j);
    }
    float w1r[10];
    {   const int j = t & 31, q = t >> 5;
        #pragma unroll
        for (int k = 0; k < 10; ++k) w1r[k] = LDF<F>(a.W[1], (q * 10 + k) * 32 + j);
    }
    float w2r[3];
    {   const int j = t & 15, q = t >> 4;
        #pragma unroll
        for (int k = 0; k < 3; ++k) w2r[k] = LDF<F>(a.W[2], (q * 3 + k) * 16 + j);
    }
    float w3r;
    {   const int j = t & 7, q = t >> 3;
        w3r = LDF<F>(a.W[3], q * 8 + j);
    }
    float w4r = (t < 24) ? LDF<F>(a.W[4], t) : 0.f;
    float b0r = (t < 64) ? LDF<F>(a.bias[0], t) : 0.f;
    float b1r = (t < 32) ? LDF<F>(a.bias[1], t) : 0.f;
    float b2r = (t < 16) ? LDF<F>(a.bias[2], t) : 0.f;
    float b3r = (t < 8)  ? LDF<F>(a.bias[3], t) : 0.f;
    float b4r = (t == 0) ? LDF<F>(a.bias[4], 0) : 0.f;

    // content-FC weights: static flen per branch (keeps fcw in registers)
    float fcw[48];
    float fcb = 0.f;
    if (t < 16) {
        fcb = LDF<F>(a.fc_b[0], t);
        #pragma unroll
        for (int k = 0; k < 16; ++k) fcw[k] = LDF<F>(a.fc_w[0], k * 16 + t);
    } else if (t < 32) {
        const int j = t & 15;
        fcb = LDF<F>(a.fc_b[1], j);
        #pragma unroll
        for (int k = 0; k < 32; ++k) fcw[k] = LDF<F>(a.fc_w[1], k * 16 + j);
    } else if (t < 48) {
        const int j = t & 15;
        fcb = LDF<F>(a.fc_b[2], j);
        #pragma unroll
        for (int k = 0; k < 48; ++k) fcw[k] = LDF<F>(a.fc_w[2], k * 16 + j);
    } else if (t < 64) {
        const int j = t & 15;
        fcb = LDF<F>(a.fc_b[3], j);
        #pragma unroll
        for (int k = 0; k < 48; ++k) fcw[k] = LDF<F>(a.fc_w[3], k * 16 + j);
    } else if (t < 80) {
        const int j = t & 15;
        fcb = LDF<F>(a.fc_b[4], j);
        #pragma unroll
        for (int k = 0; k < 48; ++k) fcw[k] = LDF<F>(a.fc_w[4], k * 16 + j);
    }

    // ================= E: embeddings + z staging =================
    if (t < 48) {
        const int g = t >> 4, j = t & 15;
        const void* v  = (g == 0) ? a.emb_s_v : (g == 1) ? a.emb_t_v : a.emb_c_v;
        const void* gp = (g == 0) ? a.emb_s_g : (g == 1) ? a.emb_t_g : a.emb_c_g;
        float gain = LDF<F>(gp, row);
        float vr[16];
        #pragma unroll
        for (int k = 0; k < 16; ++k) vr[k] = LDF<F>(v, row * 16 + k);
        float n2 = 0.f;
        #pragma unroll
        for (int k = 0; k < 16; ++k) n2 += vr[k] * vr[k];
        sm.cat3[t] = gain * vr[j] * rsqrtf(n2);
    } else if (t < 176) {
        sm.xa[t - 48] = zr;
    }
    __syncthreads();

    // ================= C: content FCs =================
    if (t < 16) {                       // c0 -> straight into xa[128..144)
        float acc = fcb;
        #pragma unroll
        for (int k = 0; k < 16; ++k) acc += sm.cat3[k] * fcw[k];
        sm.xa[128 + t] = acc;
    } else if (t < 32) {                // c1
        const int j = t & 15;
        float acc = fcb;
        #pragma unroll
        for (int k = 0; k < 32; ++k) acc += sm.cat3[k] * fcw[k];
        sm.contents[16 + j] = acc;
    } else if (t < 80) {                // c2, c3, c4
        const int i = t >> 4, j = t & 15;
        float acc = fcb;
        #pragma unroll
        for (int k = 0; k < 48; ++k) acc += sm.cat3[k] * fcw[k];
        sm.contents[i * 16 + j] = acc;
    }
    __syncthreads();

    // ================= L0: 144 -> 64, 4-way split-K =================
    {
        const int q = t >> 6;
        float acc = 0.f;
        #pragma unroll
        for (int k = 0; k < 36; ++k) acc += sm.xa[q * 36 + k] * w0r[k];
        sm.partial[t] = acc;
    }
    __syncthreads();
    if (t < 64) {
        float acc = b0r + sm.partial[t] + sm.partial[64 + t] + sm.partial[128 + t] + sm.partial[192 + t];
        sm.xb[t] = lrelu(acc);
    } else if (t < 80) {
        sm.xb[t] = sm.contents[16 + (t - 64)];    // c1 -> xb[64..80)
    }
    __syncthreads();

    // ================= L1: 80 -> 32, 8-way split-K =================
    {
        const int q = t >> 5;
        float acc = 0.f;
        #pragma unroll
        for (int k = 0; k < 10; ++k) acc += sm.xb[q * 10 + k] * w1r[k];
        sm.partial[t] = acc;
    }
    __syncthreads();
    if (t < 32) {
        float acc = b1r;
        #pragma unroll
        for (int q = 0; q < 8; ++q) acc += sm.partial[q * 32 + t];
        sm.xa[t] = lrelu(acc);
    } else if (t < 48) {
        sm.xa[t] = sm.contents[32 + (t - 32)];    // c2 -> xa[32..48)
    }
    __syncthreads();

    // ================= L2: 48 -> 16, 16-way split-K =================
    {
        const int q = t >> 4;
        float acc = 0.f;
        #pragma unroll
        for (int k = 0; k < 3; ++k) acc += sm.xa[q * 3 + k] * w2r[k];
        sm.partial[t] = acc;
    }
    __syncthreads();
    if (t < 16) {
        float acc = b2r;
        #pragma unroll
        for (int q = 0; q < 16; ++q) acc += sm.partial[q * 16 + t];
        sm.xb[t] = lrelu(acc);
    } else if (t < 32) {
        sm.xb[t] = sm.contents[48 + (t - 16)];    // c3 -> xb[16..32)
    }
    __syncthreads();

    // ================= L3: 32 -> 8, 32-way split-K =================
    {
        const int q = t >> 3;
        sm.partial[t] = sm.xb[q] * w3r;
    }
    __syncthreads();
    if (t < 8) {
        float acc = b3r;
        #pragma unroll
        for (int q = 0; q < 32; ++q) acc += sm.partial[q * 8 + t];
        sm.xa[t] = lrelu(acc);
    } else if (t < 24) {
        sm.xa[t] = sm.contents[64 + (t - 8)];     // c4 -> xa[8..24)
    }
    __syncthreads();

    // ================= L4: 24 -> 1, no activation =================
    if (t < 24) sm.partial[t] = sm.xa[t] * w4r;
    __syncthreads();
    if (t == 0) {
        float acc = b4r;
        #pragma unroll
        for (int k = 0; k < 24; ++k) acc += sm.partial[k];
        sm.res = acc;
    }
    __syncthreads();

    // ================= fill this block's 32 KB slice =================
    const float v = sm.res;
    const float4 val = make_float4(v, v, v, v);
    float4* __restrict__ o = reinterpret_cast<float4*>(out) + (size_t)b * 16384 + slice * 2048;
    #pragma unroll
    for (int k = 0; k < 8; ++k) o[k * 256 + t] = val;
}

__global__ __launch_bounds__(256) void fgl_fused_kernel(ChainArgs a, float* __restrict__ out)
{
    const int b = blockIdx.x >> 3;       // batch
    const int slice = blockIdx.x & 7;    // 1/8 of the batch's output
    const int t = threadIdx.x;

    __shared__ Smem sm;
    __shared__ int FI_s;

    // dtype sniff (validated rounds 3-4):
    //  F: any of z's first 32 words with bf16-exponent(low half) >= 0x89 -> f32.
    //  I: contrasts values 0..199; int64 => 32 high words all zero.
    if (t < 64) {
        bool fcond = false, icond = false;
        if (t < 32) {
            unsigned int wz = ((const unsigned int*)a.z)[t];
            fcond = ((wz >> 7) & 0xFF) >= 0x89;
            icond = (((const unsigned int*)a.contrasts)[2 * t + 1] != 0u);
        }
        unsigned long long bf = __ballot(fcond);
        unsigned long long bi = __ballot(icond);
        if (t == 0) FI_s = (bf ? 1 : 0) | ((bi == 0ull) ? 2 : 0);
    }
    __syncthreads();
    const int FI = FI_s;

    if (FI == 1)      chain_fill<1, 0>(a, out, b, slice, t, sm);
    else if (FI == 3) chain_fill<1, 1>(a, out, b, slice, t, sm);
    else if (FI == 0) chain_fill<0, 0>(a, out, b, slice, t, sm);
    else              chain_fill<0, 1>(a, out, b, slice, t, sm);
}

extern "C" void kernel_launch(void* const* d_in, const int* in_sizes, int n_in,
                              void* d_out, int out_size, void* d_ws, size_t ws_size,
                              hipStream_t stream) {
    ChainArgs a;
    a.z = d_in[0];
    a.studies = d_in[1];
    a.tasks = d_in[2];
    a.contrasts = d_in[3];
    // d_in[4..8] = p0..p4 — mathematically irrelevant
    a.emb_s_v = d_in[9];  a.emb_s_g = d_in[10];
    a.emb_t_v = d_in[11]; a.emb_t_g = d_in[12];
    a.emb_c_v = d_in[13]; a.emb_c_g = d_in[14];
    for (int i = 0; i < 5; ++i) {
        a.fc_w[i] = d_in[15 + 2 * i];
        a.fc_b[i] = d_in[16 + 2 * i];
        a.W[i]    = d_in[25 + 2 * i];
        a.bias[i] = d_in[26 + 2 * i];
    }
    // 512 blocks: 64 batches x 8 slices; each block = chain + 32 KB fill.
    fgl_fused_kernel<<<512, 256, 0, stream>>>(a, (float*)d_out);
}